// Round 1
// baseline (576.645 us; speedup 1.0000x reference)
//
#include <hip/hip_runtime.h>
#include <math.h>

#define T_TOK 256
#define H_DIM 1024
#define E_NUM 64
#define I_DIM 512
#define SI_DIM 2048

typedef __attribute__((ext_vector_type(8))) short short8;
typedef __attribute__((ext_vector_type(8))) __bf16 bf16x8;
typedef __attribute__((ext_vector_type(4))) float floatx4;
typedef __attribute__((ext_vector_type(4))) unsigned short ushort4v;

// float -> bf16 round-to-nearest-even
static __device__ __forceinline__ unsigned short f2bf(float f) {
  unsigned u = __float_as_uint(f);
  u += 0x7FFFu + ((u >> 16) & 1u);
  return (unsigned short)(u >> 16);
}

static __device__ __forceinline__ bf16x8 pack_bf(floatx4 lo, floatx4 hi) {
  short8 r;
  r[0] = (short)f2bf(lo[0]); r[1] = (short)f2bf(lo[1]);
  r[2] = (short)f2bf(lo[2]); r[3] = (short)f2bf(lo[3]);
  r[4] = (short)f2bf(hi[0]); r[5] = (short)f2bf(hi[1]);
  r[6] = (short)f2bf(hi[2]); r[7] = (short)f2bf(hi[3]);
  return __builtin_bit_cast(bf16x8, r);
}

static __device__ __forceinline__ floatx4 mfma16(bf16x8 a, bf16x8 b, floatx4 c) {
  return __builtin_amdgcn_mfma_f32_16x16x32_bf16(a, b, c, 0, 0, 0);
}

// ---------------------------------------------------------------------------
// Kernel 1: gate matmul (fp64 accurate) + DeepSeek-V3 noaux_tc routing.
// One block (1 wave of 64 threads) per token; lane e owns expert e.
// Also converts x row to bf16 for the MFMA kernels.
// ---------------------------------------------------------------------------
__global__ __launch_bounds__(64) void gate_route_kernel(
    const float* __restrict__ x, const float* __restrict__ gw,
    const float* __restrict__ ebias, unsigned short* __restrict__ xbf,
    int* __restrict__ cnt, int* __restrict__ tok_list,
    float* __restrict__ wt_list) {
  const int t = blockIdx.x;
  const int lane = threadIdx.x;  // 0..63
  __shared__ float xs[H_DIM];

  const floatx4* xr = (const floatx4*)(x + (size_t)t * H_DIM);
  for (int i = lane; i < H_DIM / 4; i += 64) {
    floatx4 v = xr[i];
    xs[4 * i + 0] = v[0]; xs[4 * i + 1] = v[1];
    xs[4 * i + 2] = v[2]; xs[4 * i + 3] = v[3];
    ushort4v b;
    b[0] = f2bf(v[0]); b[1] = f2bf(v[1]); b[2] = f2bf(v[2]); b[3] = f2bf(v[3]);
    ((ushort4v*)(xbf + (size_t)t * H_DIM))[i] = b;
  }
  __syncthreads();

  // logits[t][lane] in fp64 (routing decisions must not flip vs numpy ref)
  const floatx4* wr = (const floatx4*)(gw + (size_t)lane * H_DIM);
  double acc = 0.0;
  for (int i = 0; i < H_DIM / 4; ++i) {
    floatx4 w = wr[i];
    acc += (double)xs[4 * i + 0] * (double)w[0];
    acc += (double)xs[4 * i + 1] * (double)w[1];
    acc += (double)xs[4 * i + 2] * (double)w[2];
    acc += (double)xs[4 * i + 3] * (double)w[3];
  }
  const double score = 1.0 / (1.0 + exp(-acc));
  const double swb = score + (double)ebias[lane];

  // top-2 sum within each 8-lane group (butterfly, stays inside group)
  double m1 = swb, m2 = -1.0e300;
  #pragma unroll
  for (int d = 1; d < 8; d <<= 1) {
    double o1 = __shfl_xor(m1, d);
    double o2 = __shfl_xor(m2, d);
    double hi = fmax(m1, o1), lo = fmin(m1, o1);
    m1 = hi;
    m2 = fmax(lo, fmax(m2, o2));
  }
  const double gscore = m1 + m2;

  // every lane gathers the 8 group scores, redundantly picks top-4 groups
  double gs[8];
  #pragma unroll
  for (int j = 0; j < 8; ++j) gs[j] = __shfl(gscore, j << 3);
  unsigned gsel = 0;
  #pragma unroll
  for (int it = 0; it < 4; ++it) {
    int best = 0; double bv = -1.0e300;
    #pragma unroll
    for (int j = 0; j < 8; ++j) {
      bool taken = (gsel >> j) & 1u;
      if (!taken && gs[j] > bv) { bv = gs[j]; best = j; }
    }
    gsel |= 1u << best;
  }

  // top-6 experts among allowed groups (6 rounds of wave argmax, ties->low idx)
  double key = ((gsel >> (lane >> 3)) & 1u) ? swb : -1.0e300;
  int selected = 0;
  for (int it = 0; it < 6; ++it) {
    double v = key; int idx = lane;
    #pragma unroll
    for (int d = 1; d < 64; d <<= 1) {
      double ov = __shfl_xor(v, d);
      int oi = __shfl_xor(idx, d);
      if (ov > v || (ov == v && oi < idx)) { v = ov; idx = oi; }
    }
    if (lane == idx) { selected = 1; key = -1.0e300; }
  }

  double ssum = selected ? score : 0.0;
  #pragma unroll
  for (int d = 1; d < 64; d <<= 1) ssum += __shfl_xor(ssum, d);

  if (selected) {
    float wgt = (float)(score / (ssum + 1e-20) * 2.5);
    int p = atomicAdd(&cnt[lane], 1);
    tok_list[lane * T_TOK + p] = t;
    wt_list[lane * T_TOK + p] = wgt;
  }
}

// ---------------------------------------------------------------------------
// Kernel 2: shared-expert gate/up. act_s[t][si] = silu(x@wsg^T) * (x@wsu^T)
// Block = 4 waves stacked in M (covers all 256 tokens) x 16-col N strip,
// so each weight element is fetched once per block (L1 dedups across waves).
// ---------------------------------------------------------------------------
__global__ __launch_bounds__(256) void shared_gu_kernel(
    const unsigned short* __restrict__ xbf, const float* __restrict__ wsg,
    const float* __restrict__ wsu, unsigned short* __restrict__ act_s) {
  const int nstrip = blockIdx.x;        // 0..127
  const int wave = threadIdx.x >> 6;    // 0..3 -> M offset
  const int lane = threadIdx.x & 63;
  const int q = lane >> 4, c = lane & 15;
  const int n = nstrip * 16 + c;
  const int mbase = wave * 64;

  floatx4 accg[4], accu[4];
  #pragma unroll
  for (int i = 0; i < 4; ++i) { accg[i] = (floatx4)0.0f; accu[i] = (floatx4)0.0f; }

  const float* gr = wsg + (size_t)n * H_DIM;
  const float* ur = wsu + (size_t)n * H_DIM;
  for (int k = 0; k < H_DIM; k += 32) {
    const int ko = k + q * 8;
    floatx4 g0 = *(const floatx4*)(gr + ko);
    floatx4 g1 = *(const floatx4*)(gr + ko + 4);
    floatx4 u0 = *(const floatx4*)(ur + ko);
    floatx4 u1 = *(const floatx4*)(ur + ko + 4);
    bf16x8 bg = pack_bf(g0, g1);
    bf16x8 bu = pack_bf(u0, u1);
    #pragma unroll
    for (int ms = 0; ms < 4; ++ms) {
      bf16x8 a = *(const bf16x8*)(xbf + (size_t)(mbase + ms * 16 + c) * H_DIM + ko);
      accg[ms] = mfma16(a, bg, accg[ms]);
      accu[ms] = mfma16(a, bu, accu[ms]);
    }
  }
  #pragma unroll
  for (int ms = 0; ms < 4; ++ms) {
    #pragma unroll
    for (int r = 0; r < 4; ++r) {
      int m = mbase + ms * 16 + q * 4 + r;
      float g = accg[ms][r], u = accu[ms][r];
      float a = g / (1.0f + __expf(-g)) * u;
      act_s[(size_t)m * SI_DIM + n] = f2bf(a);
    }
  }
}

// ---------------------------------------------------------------------------
// Kernel 3: shared-expert down proj; WRITES d_out (=), runs before routed add.
// ---------------------------------------------------------------------------
__global__ __launch_bounds__(256) void shared_down_kernel(
    const unsigned short* __restrict__ act_s, const float* __restrict__ wsd,
    float* __restrict__ out) {
  const int nstrip = blockIdx.x;  // 0..63 over H
  const int wave = threadIdx.x >> 6;
  const int lane = threadIdx.x & 63;
  const int q = lane >> 4, c = lane & 15;
  const int h = nstrip * 16 + c;
  const int mbase = wave * 64;

  floatx4 acc[4];
  #pragma unroll
  for (int i = 0; i < 4; ++i) acc[i] = (floatx4)0.0f;

  const float* dr = wsd + (size_t)h * SI_DIM;
  for (int k = 0; k < SI_DIM; k += 32) {
    const int ko = k + q * 8;
    floatx4 d0 = *(const floatx4*)(dr + ko);
    floatx4 d1 = *(const floatx4*)(dr + ko + 4);
    bf16x8 bd = pack_bf(d0, d1);
    #pragma unroll
    for (int ms = 0; ms < 4; ++ms) {
      bf16x8 a = *(const bf16x8*)(act_s + (size_t)(mbase + ms * 16 + c) * SI_DIM + ko);
      acc[ms] = mfma16(a, bd, acc[ms]);
    }
  }
  #pragma unroll
  for (int ms = 0; ms < 4; ++ms) {
    #pragma unroll
    for (int r = 0; r < 4; ++r) {
      out[(size_t)(mbase + ms * 16 + q * 4 + r) * H_DIM + h] = acc[ms][r];
    }
  }
}

// ---------------------------------------------------------------------------
// Kernel 4: routed gate/up per expert, gathered token rows (M-tile of 32 so
// weights stream once for n_e<=32). act_r[e][m][i] bf16.
// ---------------------------------------------------------------------------
__global__ __launch_bounds__(256) void routed_gu_kernel(
    const unsigned short* __restrict__ xbf, const float* __restrict__ w1,
    const float* __restrict__ w3, const int* __restrict__ cnt,
    const int* __restrict__ tok_list, unsigned short* __restrict__ act_r) {
  const int e = blockIdx.x >> 3;
  const int nb = (blockIdx.x & 7) * 64;
  const int wave = threadIdx.x >> 6;
  const int lane = threadIdx.x & 63;
  const int q = lane >> 4, c = lane & 15;
  const int n = nb + wave * 16 + c;  // I index
  const int ne = cnt[e];
  const float* grow = w1 + ((size_t)e * I_DIM + n) * H_DIM;
  const float* urow = w3 + ((size_t)e * I_DIM + n) * H_DIM;
  const int* tl = tok_list + e * T_TOK;
  unsigned short* ap = act_r + (size_t)e * T_TOK * I_DIM;

  for (int m0 = 0; m0 < ne; m0 += 32) {
    int r0 = m0 + c, r1 = m0 + 16 + c;
    int t0 = (r0 < ne) ? tl[r0] : 0;
    int t1 = (r1 < ne) ? tl[r1] : 0;
    const unsigned short* a0p = xbf + (size_t)t0 * H_DIM;
    const unsigned short* a1p = xbf + (size_t)t1 * H_DIM;
    floatx4 ag0 = (floatx4)0.0f, ag1 = (floatx4)0.0f;
    floatx4 au0 = (floatx4)0.0f, au1 = (floatx4)0.0f;
    for (int k = 0; k < H_DIM; k += 32) {
      const int ko = k + q * 8;
      floatx4 g0 = *(const floatx4*)(grow + ko);
      floatx4 g1 = *(const floatx4*)(grow + ko + 4);
      floatx4 u0 = *(const floatx4*)(urow + ko);
      floatx4 u1 = *(const floatx4*)(urow + ko + 4);
      bf16x8 bg = pack_bf(g0, g1);
      bf16x8 bu = pack_bf(u0, u1);
      bf16x8 a0 = *(const bf16x8*)(a0p + ko);
      bf16x8 a1 = *(const bf16x8*)(a1p + ko);
      ag0 = mfma16(a0, bg, ag0);
      ag1 = mfma16(a1, bg, ag1);
      au0 = mfma16(a0, bu, au0);
      au1 = mfma16(a1, bu, au1);
    }
    #pragma unroll
    for (int s = 0; s < 2; ++s) {
      floatx4 g = s ? ag1 : ag0;
      floatx4 u = s ? au1 : au0;
      #pragma unroll
      for (int r = 0; r < 4; ++r) {
        int m = m0 + s * 16 + q * 4 + r;
        if (m < ne) {
          float gg = g[r], uu = u[r];
          float a = gg / (1.0f + __expf(-gg)) * uu;
          ap[(size_t)m * I_DIM + n] = f2bf(a);
        }
      }
    }
  }
}

// ---------------------------------------------------------------------------
// Kernel 5: routed down proj + weighted combine (atomicAdd onto shared output)
// ---------------------------------------------------------------------------
__global__ __launch_bounds__(256) void routed_down_kernel(
    const unsigned short* __restrict__ act_r, const float* __restrict__ w2,
    const int* __restrict__ cnt, const int* __restrict__ tok_list,
    const float* __restrict__ wt_list, float* __restrict__ out) {
  const int e = blockIdx.x >> 4;
  const int nb = (blockIdx.x & 15) * 64;
  const int wave = threadIdx.x >> 6;
  const int lane = threadIdx.x & 63;
  const int q = lane >> 4, c = lane & 15;
  const int h = nb + wave * 16 + c;
  const int ne = cnt[e];
  const float* wrow = w2 + ((size_t)e * H_DIM + h) * I_DIM;
  const unsigned short* ap = act_r + (size_t)e * T_TOK * I_DIM;
  const int* tl = tok_list + e * T_TOK;
  const float* wl = wt_list + e * T_TOK;

  for (int m0 = 0; m0 < ne; m0 += 32) {
    int ra = m0 + c;                                        // pad rows read
    int rb = m0 + 16 + c; if (rb > T_TOK - 1) rb = T_TOK - 1;  // garbage, dropped
    floatx4 acc0 = (floatx4)0.0f, acc1 = (floatx4)0.0f;
    for (int k = 0; k < I_DIM; k += 32) {
      const int ko = k + q * 8;
      floatx4 w0 = *(const floatx4*)(wrow + ko);
      floatx4 w1v = *(const floatx4*)(wrow + ko + 4);
      bf16x8 bw = pack_bf(w0, w1v);
      bf16x8 a0 = *(const bf16x8*)(ap + (size_t)ra * I_DIM + ko);
      bf16x8 a1 = *(const bf16x8*)(ap + (size_t)rb * I_DIM + ko);
      acc0 = mfma16(a0, bw, acc0);
      acc1 = mfma16(a1, bw, acc1);
    }
    #pragma unroll
    for (int s = 0; s < 2; ++s) {
      floatx4 d = s ? acc1 : acc0;
      #pragma unroll
      for (int r = 0; r < 4; ++r) {
        int m = m0 + s * 16 + q * 4 + r;
        if (m < ne) {
          atomicAdd(&out[(size_t)tl[m] * H_DIM + h], d[r] * wl[m]);
        }
      }
    }
  }
}

extern "C" void kernel_launch(void* const* d_in, const int* in_sizes, int n_in,
                              void* d_out, int out_size, void* d_ws, size_t ws_size,
                              hipStream_t stream) {
  const float* x   = (const float*)d_in[0];
  const float* gw  = (const float*)d_in[1];
  const float* eb  = (const float*)d_in[2];
  const float* w1  = (const float*)d_in[3];
  const float* w3  = (const float*)d_in[4];
  const float* w2  = (const float*)d_in[5];
  const float* wsg = (const float*)d_in[6];
  const float* wsu = (const float*)d_in[7];
  const float* wsd = (const float*)d_in[8];
  float* out = (float*)d_out;

  char* ws = (char*)d_ws;
  // ws layout (bytes): total ~17.7 MB
  unsigned short* xbf   = (unsigned short*)(ws);                 // 512 KB
  unsigned short* act_s = (unsigned short*)(ws + 524288);        // 1 MB
  int*   cnt            = (int*)(ws + 1572864);                  // 256 B
  int*   tok            = (int*)(ws + 1573120);                  // 64 KB
  float* wt             = (float*)(ws + 1638656);                // 64 KB
  unsigned short* act_r = (unsigned short*)(ws + 1704192);       // 16 MB

  hipMemsetAsync(cnt, 0, E_NUM * sizeof(int), stream);
  gate_route_kernel<<<dim3(T_TOK), dim3(64), 0, stream>>>(x, gw, eb, xbf, cnt, tok, wt);
  shared_gu_kernel<<<dim3(SI_DIM / 16), dim3(256), 0, stream>>>(xbf, wsg, wsu, act_s);
  shared_down_kernel<<<dim3(H_DIM / 16), dim3(256), 0, stream>>>(act_s, wsd, out);
  routed_gu_kernel<<<dim3(E_NUM * (I_DIM / 64)), dim3(256), 0, stream>>>(xbf, w1, w3, cnt, tok, act_r);
  routed_down_kernel<<<dim3(E_NUM * (H_DIM / 64)), dim3(256), 0, stream>>>(act_r, w2, cnt, tok, wt, out);
}

// Round 2
// 555.306 us; speedup vs baseline: 1.0384x; 1.0384x over previous
//
#include <hip/hip_runtime.h>
#include <math.h>

#define T_TOK 256
#define H_DIM 1024
#define E_NUM 64
#define I_DIM 512
#define SI_DIM 2048

#define BN 64
#define BM 32
#define BK 64
#define LDB 72   // bf16 elems per LDS row; 144B stride keeps b128 reads 16B-aligned

typedef __attribute__((ext_vector_type(8))) short short8;
typedef __attribute__((ext_vector_type(8))) __bf16 bf16x8;
typedef __attribute__((ext_vector_type(4))) float floatx4;
typedef __attribute__((ext_vector_type(4))) unsigned short ushort4v;

// float -> bf16 round-to-nearest-even
static __device__ __forceinline__ unsigned short f2bf(float f) {
  unsigned u = __float_as_uint(f);
  u += 0x7FFFu + ((u >> 16) & 1u);
  return (unsigned short)(u >> 16);
}

static __device__ __forceinline__ ushort4v pack4(floatx4 v) {
  ushort4v b;
  b[0] = f2bf(v[0]); b[1] = f2bf(v[1]); b[2] = f2bf(v[2]); b[3] = f2bf(v[3]);
  return b;
}

static __device__ __forceinline__ floatx4 mfma16(bf16x8 a, bf16x8 b, floatx4 c) {
  return __builtin_amdgcn_mfma_f32_16x16x32_bf16(a, b, c, 0, 0, 0);
}

// ---------------------------------------------------------------------------
// Kernel 1: gate matmul (fp64, 4-way H-split) + noaux_tc routing + x->bf16.
// Block = 256 threads per token: thread j handles expert j&63, H-chunk j>>6.
// ---------------------------------------------------------------------------
__global__ __launch_bounds__(256) void gate_route_kernel(
    const float* __restrict__ x, const float* __restrict__ gw,
    const float* __restrict__ ebias, unsigned short* __restrict__ xbf,
    int* __restrict__ cnt, int* __restrict__ tok_list,
    float* __restrict__ wt_list) {
  const int t = blockIdx.x;
  const int j = threadIdx.x;
  __shared__ float xs[H_DIM];
  __shared__ double pd[4 * 64];

  floatx4 v = ((const floatx4*)(x + (size_t)t * H_DIM))[j];
  xs[4 * j + 0] = v[0]; xs[4 * j + 1] = v[1];
  xs[4 * j + 2] = v[2]; xs[4 * j + 3] = v[3];
  ((ushort4v*)(xbf + (size_t)t * H_DIM))[j] = pack4(v);
  __syncthreads();

  const int e = j & 63, ch = j >> 6;
  const float* wr = gw + (size_t)e * H_DIM + ch * 256;
  const float* xc = xs + ch * 256;
  double acc = 0.0;
  for (int i = 0; i < 64; ++i) {
    floatx4 w = ((const floatx4*)wr)[i];
    acc += (double)xc[4 * i + 0] * (double)w[0]
         + (double)xc[4 * i + 1] * (double)w[1]
         + (double)xc[4 * i + 2] * (double)w[2]
         + (double)xc[4 * i + 3] * (double)w[3];
  }
  pd[ch * 64 + e] = acc;
  __syncthreads();

  if (j < 64) {
    const int lane = j;
    const double logit = pd[lane] + pd[64 + lane] + pd[128 + lane] + pd[192 + lane];
    const double score = 1.0 / (1.0 + exp(-logit));
    const double swb = score + (double)ebias[lane];

    // top-2 sum within each 8-lane group
    double m1 = swb, m2 = -1.0e300;
    #pragma unroll
    for (int d = 1; d < 8; d <<= 1) {
      double o1 = __shfl_xor(m1, d);
      double o2 = __shfl_xor(m2, d);
      double hi = fmax(m1, o1), lo = fmin(m1, o1);
      m1 = hi;
      m2 = fmax(lo, fmax(m2, o2));
    }
    const double gscore = m1 + m2;

    double gs[8];
    #pragma unroll
    for (int g = 0; g < 8; ++g) gs[g] = __shfl(gscore, g << 3);
    unsigned gsel = 0;
    #pragma unroll
    for (int it = 0; it < 4; ++it) {
      int best = 0; double bv = -1.0e300;
      #pragma unroll
      for (int g = 0; g < 8; ++g) {
        bool taken = (gsel >> g) & 1u;
        if (!taken && gs[g] > bv) { bv = gs[g]; best = g; }
      }
      gsel |= 1u << best;
    }

    double key = ((gsel >> (lane >> 3)) & 1u) ? swb : -1.0e300;
    int selected = 0;
    for (int it = 0; it < 6; ++it) {
      double vv = key; int idx = lane;
      #pragma unroll
      for (int d = 1; d < 64; d <<= 1) {
        double ov = __shfl_xor(vv, d);
        int oi = __shfl_xor(idx, d);
        if (ov > vv || (ov == vv && oi < idx)) { vv = ov; idx = oi; }
      }
      if (lane == idx) { selected = 1; key = -1.0e300; }
    }

    double ssum = selected ? score : 0.0;
    #pragma unroll
    for (int d = 1; d < 64; d <<= 1) ssum += __shfl_xor(ssum, d);

    if (selected) {
      float wgt = (float)(score / (ssum + 1e-20) * 2.5);
      int p = atomicAdd(&cnt[lane], 1);
      tok_list[lane * T_TOK + p] = t;
      wt_list[lane * T_TOK + p] = wgt;
    }
  }
}

// ---------------------------------------------------------------------------
// Kernel 2: routed gate/up. LDS-staged canonical GEMM. Block: expert e x 64
// I-columns; waves each own 16 cols; m-tiles of 32 gathered token rows.
// ---------------------------------------------------------------------------
__global__ __launch_bounds__(256) void routed_gu_kernel(
    const unsigned short* __restrict__ xbf, const float* __restrict__ w1,
    const float* __restrict__ w3, const int* __restrict__ cnt,
    const int* __restrict__ tok_list, unsigned short* __restrict__ act_r) {
  __shared__ unsigned short sBg[BN * LDB];
  __shared__ unsigned short sBu[BN * LDB];
  __shared__ unsigned short sA[BM * LDB];
  __shared__ int stok[BM];

  const int e = blockIdx.x >> 3;
  const int n0 = (blockIdx.x & 7) * BN;
  const int j = threadIdx.x;
  const int wv = j >> 6, lane = j & 63;
  const int q = lane >> 4, c = lane & 15;
  const int ne = cnt[e];
  const int* tl = tok_list + e * T_TOK;
  unsigned short* ap = act_r + (size_t)e * T_TOK * I_DIM;
  const float* wgB = w1 + ((size_t)e * I_DIM + n0) * H_DIM;
  const float* wuB = w3 + ((size_t)e * I_DIM + n0) * H_DIM;

  const int wrow = j >> 4;          // 0..15
  const int wcol = (j & 15) * 4;    // 0..60
  const int arow = j >> 3;          // 0..31
  const int acol = (j & 7) * 8;     // 0..56

  for (int m0 = 0; m0 < ne; m0 += BM) {
    __syncthreads();  // protect stok vs previous epilogue readers
    if (j < BM) {
      int r = m0 + j;
      stok[j] = (r < ne) ? tl[r] : 0;
    }
    floatx4 ag0 = (floatx4)0.0f, ag1 = (floatx4)0.0f;
    floatx4 au0 = (floatx4)0.0f, au1 = (floatx4)0.0f;
    for (int k0 = 0; k0 < H_DIM; k0 += BK) {
      __syncthreads();
      #pragma unroll
      for (int p = 0; p < 4; ++p) {
        const int r = p * 16 + wrow;
        floatx4 g = *(const floatx4*)(wgB + (size_t)r * H_DIM + k0 + wcol);
        floatx4 u = *(const floatx4*)(wuB + (size_t)r * H_DIM + k0 + wcol);
        *(ushort4v*)(sBg + r * LDB + wcol) = pack4(g);
        *(ushort4v*)(sBu + r * LDB + wcol) = pack4(u);
      }
      *(bf16x8*)(sA + arow * LDB + acol) =
          *(const bf16x8*)(xbf + (size_t)stok[arow] * H_DIM + k0 + acol);
      __syncthreads();
      #pragma unroll
      for (int kk = 0; kk < BK; kk += 32) {
        const int ko = kk + q * 8;
        bf16x8 bg = *(const bf16x8*)(sBg + (wv * 16 + c) * LDB + ko);
        bf16x8 bu = *(const bf16x8*)(sBu + (wv * 16 + c) * LDB + ko);
        bf16x8 a0 = *(const bf16x8*)(sA + c * LDB + ko);
        bf16x8 a1 = *(const bf16x8*)(sA + (16 + c) * LDB + ko);
        ag0 = mfma16(a0, bg, ag0);
        ag1 = mfma16(a1, bg, ag1);
        au0 = mfma16(a0, bu, au0);
        au1 = mfma16(a1, bu, au1);
      }
    }
    #pragma unroll
    for (int s = 0; s < 2; ++s) {
      floatx4 g = s ? ag1 : ag0;
      floatx4 u = s ? au1 : au0;
      #pragma unroll
      for (int r = 0; r < 4; ++r) {
        const int m = m0 + s * 16 + q * 4 + r;
        if (m < ne) {
          float gg = g[r], uu = u[r];
          float a = gg / (1.0f + __expf(-gg)) * uu;
          ap[(size_t)m * I_DIM + n0 + wv * 16 + c] = f2bf(a);
        }
      }
    }
  }
}

// ---------------------------------------------------------------------------
// Kernel 3: shared gate/up, same staged structure; grid covers 32 n-tiles x
// 8 m-tiles of the 256 tokens.
// ---------------------------------------------------------------------------
__global__ __launch_bounds__(256) void shared_gu_kernel(
    const unsigned short* __restrict__ xbf, const float* __restrict__ wsg,
    const float* __restrict__ wsu, unsigned short* __restrict__ act_s) {
  __shared__ unsigned short sBg[BN * LDB];
  __shared__ unsigned short sBu[BN * LDB];
  __shared__ unsigned short sA[BM * LDB];

  const int n0 = (blockIdx.x & 31) * BN;
  const int m0 = (blockIdx.x >> 5) * BM;
  const int j = threadIdx.x;
  const int wv = j >> 6, lane = j & 63;
  const int q = lane >> 4, c = lane & 15;
  const float* wgB = wsg + (size_t)n0 * H_DIM;
  const float* wuB = wsu + (size_t)n0 * H_DIM;

  const int wrow = j >> 4, wcol = (j & 15) * 4;
  const int arow = j >> 3, acol = (j & 7) * 8;

  floatx4 ag0 = (floatx4)0.0f, ag1 = (floatx4)0.0f;
  floatx4 au0 = (floatx4)0.0f, au1 = (floatx4)0.0f;
  for (int k0 = 0; k0 < H_DIM; k0 += BK) {
    __syncthreads();
    #pragma unroll
    for (int p = 0; p < 4; ++p) {
      const int r = p * 16 + wrow;
      floatx4 g = *(const floatx4*)(wgB + (size_t)r * H_DIM + k0 + wcol);
      floatx4 u = *(const floatx4*)(wuB + (size_t)r * H_DIM + k0 + wcol);
      *(ushort4v*)(sBg + r * LDB + wcol) = pack4(g);
      *(ushort4v*)(sBu + r * LDB + wcol) = pack4(u);
    }
    *(bf16x8*)(sA + arow * LDB + acol) =
        *(const bf16x8*)(xbf + (size_t)(m0 + arow) * H_DIM + k0 + acol);
    __syncthreads();
    #pragma unroll
    for (int kk = 0; kk < BK; kk += 32) {
      const int ko = kk + q * 8;
      bf16x8 bg = *(const bf16x8*)(sBg + (wv * 16 + c) * LDB + ko);
      bf16x8 bu = *(const bf16x8*)(sBu + (wv * 16 + c) * LDB + ko);
      bf16x8 a0 = *(const bf16x8*)(sA + c * LDB + ko);
      bf16x8 a1 = *(const bf16x8*)(sA + (16 + c) * LDB + ko);
      ag0 = mfma16(a0, bg, ag0);
      ag1 = mfma16(a1, bg, ag1);
      au0 = mfma16(a0, bu, au0);
      au1 = mfma16(a1, bu, au1);
    }
  }
  #pragma unroll
  for (int s = 0; s < 2; ++s) {
    floatx4 g = s ? ag1 : ag0;
    floatx4 u = s ? au1 : au0;
    #pragma unroll
    for (int r = 0; r < 4; ++r) {
      const int m = m0 + s * 16 + q * 4 + r;
      float gg = g[r], uu = u[r];
      float a = gg / (1.0f + __expf(-gg)) * uu;
      act_s[(size_t)m * SI_DIM + n0 + wv * 16 + c] = f2bf(a);
    }
  }
}

// ---------------------------------------------------------------------------
// Kernel 4: shared down; K-split x2 across blocks, atomicAdd into zeroed out.
// ---------------------------------------------------------------------------
__global__ __launch_bounds__(256) void shared_down_kernel(
    const unsigned short* __restrict__ act_s, const float* __restrict__ wsd,
    float* __restrict__ out) {
  __shared__ unsigned short sB[BN * LDB];
  __shared__ unsigned short sA[BM * LDB];

  const int n0 = (blockIdx.x & 15) * BN;
  const int m0 = ((blockIdx.x >> 4) & 7) * BM;
  const int kh = blockIdx.x >> 7;
  const int kbeg = kh * (SI_DIM / 2);
  const int j = threadIdx.x;
  const int wv = j >> 6, lane = j & 63;
  const int q = lane >> 4, c = lane & 15;
  const float* wB = wsd + (size_t)n0 * SI_DIM;

  const int wrow = j >> 4, wcol = (j & 15) * 4;
  const int arow = j >> 3, acol = (j & 7) * 8;

  floatx4 ac0 = (floatx4)0.0f, ac1 = (floatx4)0.0f;
  for (int k0 = kbeg; k0 < kbeg + SI_DIM / 2; k0 += BK) {
    __syncthreads();
    #pragma unroll
    for (int p = 0; p < 4; ++p) {
      const int r = p * 16 + wrow;
      floatx4 w = *(const floatx4*)(wB + (size_t)r * SI_DIM + k0 + wcol);
      *(ushort4v*)(sB + r * LDB + wcol) = pack4(w);
    }
    *(bf16x8*)(sA + arow * LDB + acol) =
        *(const bf16x8*)(act_s + (size_t)(m0 + arow) * SI_DIM + k0 + acol);
    __syncthreads();
    #pragma unroll
    for (int kk = 0; kk < BK; kk += 32) {
      const int ko = kk + q * 8;
      bf16x8 b = *(const bf16x8*)(sB + (wv * 16 + c) * LDB + ko);
      bf16x8 a0 = *(const bf16x8*)(sA + c * LDB + ko);
      bf16x8 a1 = *(const bf16x8*)(sA + (16 + c) * LDB + ko);
      ac0 = mfma16(a0, b, ac0);
      ac1 = mfma16(a1, b, ac1);
    }
  }
  #pragma unroll
  for (int s = 0; s < 2; ++s) {
    floatx4 d = s ? ac1 : ac0;
    #pragma unroll
    for (int r = 0; r < 4; ++r) {
      const int m = m0 + s * 16 + q * 4 + r;
      atomicAdd(&out[(size_t)m * H_DIM + n0 + wv * 16 + c], d[r]);
    }
  }
}

// ---------------------------------------------------------------------------
// Kernel 5: routed down + weighted scatter-add.
// ---------------------------------------------------------------------------
__global__ __launch_bounds__(256) void routed_down_kernel(
    const unsigned short* __restrict__ act_r, const float* __restrict__ w2,
    const int* __restrict__ cnt, const int* __restrict__ tok_list,
    const float* __restrict__ wt_list, float* __restrict__ out) {
  __shared__ unsigned short sB[BN * LDB];
  __shared__ unsigned short sA[BM * LDB];
  __shared__ int stok[BM];
  __shared__ float swl[BM];

  const int e = blockIdx.x >> 4;
  const int n0 = (blockIdx.x & 15) * BN;
  const int j = threadIdx.x;
  const int wv = j >> 6, lane = j & 63;
  const int q = lane >> 4, c = lane & 15;
  const int ne = cnt[e];
  const int* tl = tok_list + e * T_TOK;
  const float* wl = wt_list + e * T_TOK;
  const unsigned short* apb = act_r + (size_t)e * T_TOK * I_DIM;
  const float* wB = w2 + ((size_t)e * H_DIM + n0) * I_DIM;

  const int wrow = j >> 4, wcol = (j & 15) * 4;
  const int arow = j >> 3, acol = (j & 7) * 8;

  for (int m0 = 0; m0 < ne; m0 += BM) {
    __syncthreads();  // protect stok/swl vs previous epilogue readers
    if (j < BM) {
      int r = m0 + j;
      bool ok = r < ne;
      stok[j] = ok ? tl[r] : 0;
      swl[j] = ok ? wl[r] : 0.0f;
    }
    floatx4 ac0 = (floatx4)0.0f, ac1 = (floatx4)0.0f;
    for (int k0 = 0; k0 < I_DIM; k0 += BK) {
      __syncthreads();
      #pragma unroll
      for (int p = 0; p < 4; ++p) {
        const int r = p * 16 + wrow;
        floatx4 w = *(const floatx4*)(wB + (size_t)r * I_DIM + k0 + wcol);
        *(ushort4v*)(sB + r * LDB + wcol) = pack4(w);
      }
      int ar = m0 + arow;
      if (ar >= T_TOK) ar = T_TOK - 1;
      *(bf16x8*)(sA + arow * LDB + acol) =
          *(const bf16x8*)(apb + (size_t)ar * I_DIM + k0 + acol);
      __syncthreads();
      #pragma unroll
      for (int kk = 0; kk < BK; kk += 32) {
        const int ko = kk + q * 8;
        bf16x8 b = *(const bf16x8*)(sB + (wv * 16 + c) * LDB + ko);
        bf16x8 a0 = *(const bf16x8*)(sA + c * LDB + ko);
        bf16x8 a1 = *(const bf16x8*)(sA + (16 + c) * LDB + ko);
        ac0 = mfma16(a0, b, ac0);
        ac1 = mfma16(a1, b, ac1);
      }
    }
    #pragma unroll
    for (int s = 0; s < 2; ++s) {
      floatx4 d = s ? ac1 : ac0;
      #pragma unroll
      for (int r = 0; r < 4; ++r) {
        const int mi = s * 16 + q * 4 + r;
        if (m0 + mi < ne) {
          atomicAdd(&out[(size_t)stok[mi] * H_DIM + n0 + wv * 16 + c],
                    d[r] * swl[mi]);
        }
      }
    }
  }
}

extern "C" void kernel_launch(void* const* d_in, const int* in_sizes, int n_in,
                              void* d_out, int out_size, void* d_ws, size_t ws_size,
                              hipStream_t stream) {
  const float* x   = (const float*)d_in[0];
  const float* gw  = (const float*)d_in[1];
  const float* eb  = (const float*)d_in[2];
  const float* w1  = (const float*)d_in[3];
  const float* w3  = (const float*)d_in[4];
  const float* w2  = (const float*)d_in[5];
  const float* wsg = (const float*)d_in[6];
  const float* wsu = (const float*)d_in[7];
  const float* wsd = (const float*)d_in[8];
  float* out = (float*)d_out;

  char* ws = (char*)d_ws;
  unsigned short* xbf   = (unsigned short*)(ws);                 // 512 KB
  unsigned short* act_s = (unsigned short*)(ws + 524288);        // 1 MB
  int*   cnt            = (int*)(ws + 1572864);                  // 256 B
  int*   tok            = (int*)(ws + 1573120);                  // 64 KB
  float* wt             = (float*)(ws + 1638656);                // 64 KB
  unsigned short* act_r = (unsigned short*)(ws + 1704192);       // 16.8 MB

  hipMemsetAsync(cnt, 0, E_NUM * sizeof(int), stream);
  hipMemsetAsync(out, 0, (size_t)T_TOK * H_DIM * sizeof(float), stream);
  gate_route_kernel<<<dim3(T_TOK), dim3(256), 0, stream>>>(x, gw, eb, xbf, cnt, tok, wt);
  routed_gu_kernel<<<dim3(E_NUM * (I_DIM / BN)), dim3(256), 0, stream>>>(xbf, w1, w3, cnt, tok, act_r);
  shared_gu_kernel<<<dim3((SI_DIM / BN) * (T_TOK / BM)), dim3(256), 0, stream>>>(xbf, wsg, wsu, act_s);
  shared_down_kernel<<<dim3((H_DIM / BN) * (T_TOK / BM) * 2), dim3(256), 0, stream>>>(act_s, wsd, out);
  routed_down_kernel<<<dim3(E_NUM * (H_DIM / BN)), dim3(256), 0, stream>>>(act_r, w2, cnt, tok, wt, out);
}

// Round 3
// 466.208 us; speedup vs baseline: 1.2369x; 1.1911x over previous
//
#include <hip/hip_runtime.h>
#include <math.h>

#define T_TOK 256
#define H_DIM 1024
#define E_NUM 64
#define I_DIM 512
#define SI_DIM 2048

#define BN 64
#define BM 32
#define BK 64
#define LDB 72   // bf16 elems per LDS row; 144B stride keeps b128 reads 16B-aligned

typedef __attribute__((ext_vector_type(8))) short short8;
typedef __attribute__((ext_vector_type(8))) __bf16 bf16x8;
typedef __attribute__((ext_vector_type(4))) float floatx4;
typedef __attribute__((ext_vector_type(4))) unsigned short ushort4v;

// float -> bf16 round-to-nearest-even
static __device__ __forceinline__ unsigned short f2bf(float f) {
  unsigned u = __float_as_uint(f);
  u += 0x7FFFu + ((u >> 16) & 1u);
  return (unsigned short)(u >> 16);
}

static __device__ __forceinline__ ushort4v pack4(floatx4 v) {
  ushort4v b;
  b[0] = f2bf(v[0]); b[1] = f2bf(v[1]); b[2] = f2bf(v[2]); b[3] = f2bf(v[3]);
  return b;
}

static __device__ __forceinline__ floatx4 mfma16(bf16x8 a, bf16x8 b, floatx4 c) {
  return __builtin_amdgcn_mfma_f32_16x16x32_bf16(a, b, c, 0, 0, 0);
}

// ---------------------------------------------------------------------------
// Kernel 1: gate matmul (fp64, 4-way H-split) + noaux_tc routing + x->bf16.
// ---------------------------------------------------------------------------
__global__ __launch_bounds__(256) void gate_route_kernel(
    const float* __restrict__ x, const float* __restrict__ gw,
    const float* __restrict__ ebias, unsigned short* __restrict__ xbf,
    int* __restrict__ cnt, int* __restrict__ tok_list,
    float* __restrict__ wt_list) {
  const int t = blockIdx.x;
  const int j = threadIdx.x;
  __shared__ float xs[H_DIM];
  __shared__ double pd[4 * 64];

  floatx4 v = ((const floatx4*)(x + (size_t)t * H_DIM))[j];
  xs[4 * j + 0] = v[0]; xs[4 * j + 1] = v[1];
  xs[4 * j + 2] = v[2]; xs[4 * j + 3] = v[3];
  ((ushort4v*)(xbf + (size_t)t * H_DIM))[j] = pack4(v);
  __syncthreads();

  const int e = j & 63, ch = j >> 6;
  const float* wr = gw + (size_t)e * H_DIM + ch * 256;
  const float* xc = xs + ch * 256;
  double acc = 0.0;
  for (int i = 0; i < 64; ++i) {
    floatx4 w = ((const floatx4*)wr)[i];
    acc += (double)xc[4 * i + 0] * (double)w[0]
         + (double)xc[4 * i + 1] * (double)w[1]
         + (double)xc[4 * i + 2] * (double)w[2]
         + (double)xc[4 * i + 3] * (double)w[3];
  }
  pd[ch * 64 + e] = acc;
  __syncthreads();

  if (j < 64) {
    const int lane = j;
    const double logit = pd[lane] + pd[64 + lane] + pd[128 + lane] + pd[192 + lane];
    const double score = 1.0 / (1.0 + exp(-logit));
    const double swb = score + (double)ebias[lane];

    double m1 = swb, m2 = -1.0e300;
    #pragma unroll
    for (int d = 1; d < 8; d <<= 1) {
      double o1 = __shfl_xor(m1, d);
      double o2 = __shfl_xor(m2, d);
      double hi = fmax(m1, o1), lo = fmin(m1, o1);
      m1 = hi;
      m2 = fmax(lo, fmax(m2, o2));
    }
    const double gscore = m1 + m2;

    double gs[8];
    #pragma unroll
    for (int g = 0; g < 8; ++g) gs[g] = __shfl(gscore, g << 3);
    unsigned gsel = 0;
    #pragma unroll
    for (int it = 0; it < 4; ++it) {
      int best = 0; double bv = -1.0e300;
      #pragma unroll
      for (int g = 0; g < 8; ++g) {
        bool taken = (gsel >> g) & 1u;
        if (!taken && gs[g] > bv) { bv = gs[g]; best = g; }
      }
      gsel |= 1u << best;
    }

    double key = ((gsel >> (lane >> 3)) & 1u) ? swb : -1.0e300;
    int selected = 0;
    for (int it = 0; it < 6; ++it) {
      double vv = key; int idx = lane;
      #pragma unroll
      for (int d = 1; d < 64; d <<= 1) {
        double ov = __shfl_xor(vv, d);
        int oi = __shfl_xor(idx, d);
        if (ov > vv || (ov == vv && oi < idx)) { vv = ov; idx = oi; }
      }
      if (lane == idx) { selected = 1; key = -1.0e300; }
    }

    double ssum = selected ? score : 0.0;
    #pragma unroll
    for (int d = 1; d < 64; d <<= 1) ssum += __shfl_xor(ssum, d);

    if (selected) {
      float wgt = (float)(score / (ssum + 1e-20) * 2.5);
      int p = atomicAdd(&cnt[lane], 1);
      tok_list[lane * T_TOK + p] = t;
      wt_list[lane * T_TOK + p] = wgt;
    }
  }
}

// ---------------------------------------------------------------------------
// Kernel 2: routed gate/up. Register-prefetch pipelined staging:
// next K-tile's global loads issue right after the barrier and overlap the
// MFMA phase; launch_bounds(256,2) frees the register allocator (8 16B loads
// in flight per thread instead of VGPR=36 serialization).
// ---------------------------------------------------------------------------
__global__ __launch_bounds__(256, 2) void routed_gu_kernel(
    const unsigned short* __restrict__ xbf, const float* __restrict__ w1,
    const float* __restrict__ w3, const int* __restrict__ cnt,
    const int* __restrict__ tok_list, unsigned short* __restrict__ act_r) {
  __shared__ unsigned short sBg[BN * LDB];
  __shared__ unsigned short sBu[BN * LDB];
  __shared__ unsigned short sA[BM * LDB];
  __shared__ int stok[BM];

  const int e = blockIdx.x >> 3;
  const int n0 = (blockIdx.x & 7) * BN;
  const int j = threadIdx.x;
  const int wv = j >> 6, lane = j & 63;
  const int q = lane >> 4, c = lane & 15;
  const int ne = cnt[e];
  const int* tl = tok_list + e * T_TOK;
  unsigned short* ap = act_r + (size_t)e * T_TOK * I_DIM;
  const float* wgB = w1 + ((size_t)e * I_DIM + n0) * H_DIM;
  const float* wuB = w3 + ((size_t)e * I_DIM + n0) * H_DIM;

  const int wrow = j >> 4;          // 0..15
  const int wcol = (j & 15) * 4;    // 0..60
  const int arow = j >> 3;          // 0..31
  const int acol = (j & 7) * 8;     // 0..56

  for (int m0 = 0; m0 < ne; m0 += BM) {
    __syncthreads();  // prior LDS readers done
    if (j < BM) {
      int r = m0 + j;
      stok[j] = (r < ne) ? tl[r] : 0;
    }
    __syncthreads();  // stok visible
    const unsigned short* aRow = xbf + (size_t)stok[arow] * H_DIM;

    floatx4 pg[4], pu[4];
    bf16x8 pa;
    #pragma unroll
    for (int p = 0; p < 4; ++p) {
      pg[p] = *(const floatx4*)(wgB + (size_t)(p * 16 + wrow) * H_DIM + wcol);
      pu[p] = *(const floatx4*)(wuB + (size_t)(p * 16 + wrow) * H_DIM + wcol);
    }
    pa = *(const bf16x8*)(aRow + acol);

    floatx4 ag0 = (floatx4)0.0f, ag1 = (floatx4)0.0f;
    floatx4 au0 = (floatx4)0.0f, au1 = (floatx4)0.0f;
    for (int k0 = 0; k0 < H_DIM; k0 += BK) {
      if (k0) __syncthreads();  // prior MFMA phase done reading LDS
      #pragma unroll
      for (int p = 0; p < 4; ++p) {
        *(ushort4v*)(sBg + (p * 16 + wrow) * LDB + wcol) = pack4(pg[p]);
        *(ushort4v*)(sBu + (p * 16 + wrow) * LDB + wcol) = pack4(pu[p]);
      }
      *(bf16x8*)(sA + arow * LDB + acol) = pa;
      __syncthreads();
      if (k0 + BK < H_DIM) {  // prefetch next K-tile; overlaps MFMA below
        const int kn = k0 + BK;
        #pragma unroll
        for (int p = 0; p < 4; ++p) {
          pg[p] = *(const floatx4*)(wgB + (size_t)(p * 16 + wrow) * H_DIM + kn + wcol);
          pu[p] = *(const floatx4*)(wuB + (size_t)(p * 16 + wrow) * H_DIM + kn + wcol);
        }
        pa = *(const bf16x8*)(aRow + kn + acol);
      }
      #pragma unroll
      for (int kk = 0; kk < BK; kk += 32) {
        const int ko = kk + q * 8;
        bf16x8 bg = *(const bf16x8*)(sBg + (wv * 16 + c) * LDB + ko);
        bf16x8 bu = *(const bf16x8*)(sBu + (wv * 16 + c) * LDB + ko);
        bf16x8 a0 = *(const bf16x8*)(sA + c * LDB + ko);
        bf16x8 a1 = *(const bf16x8*)(sA + (16 + c) * LDB + ko);
        ag0 = mfma16(a0, bg, ag0);
        ag1 = mfma16(a1, bg, ag1);
        au0 = mfma16(a0, bu, au0);
        au1 = mfma16(a1, bu, au1);
      }
    }
    #pragma unroll
    for (int s = 0; s < 2; ++s) {
      floatx4 g = s ? ag1 : ag0;
      floatx4 u = s ? au1 : au0;
      #pragma unroll
      for (int r = 0; r < 4; ++r) {
        const int m = m0 + s * 16 + q * 4 + r;
        if (m < ne) {
          float gg = g[r], uu = u[r];
          float a = gg / (1.0f + __expf(-gg)) * uu;
          ap[(size_t)m * I_DIM + n0 + wv * 16 + c] = f2bf(a);
        }
      }
    }
  }
}

// ---------------------------------------------------------------------------
// Kernel 3: shared gate/up, same pipelined structure.
// ---------------------------------------------------------------------------
__global__ __launch_bounds__(256, 2) void shared_gu_kernel(
    const unsigned short* __restrict__ xbf, const float* __restrict__ wsg,
    const float* __restrict__ wsu, unsigned short* __restrict__ act_s) {
  __shared__ unsigned short sBg[BN * LDB];
  __shared__ unsigned short sBu[BN * LDB];
  __shared__ unsigned short sA[BM * LDB];

  const int n0 = (blockIdx.x & 31) * BN;
  const int m0 = (blockIdx.x >> 5) * BM;
  const int j = threadIdx.x;
  const int wv = j >> 6, lane = j & 63;
  const int q = lane >> 4, c = lane & 15;
  const float* wgB = wsg + (size_t)n0 * H_DIM;
  const float* wuB = wsu + (size_t)n0 * H_DIM;

  const int wrow = j >> 4, wcol = (j & 15) * 4;
  const int arow = j >> 3, acol = (j & 7) * 8;
  const unsigned short* aRow = xbf + (size_t)(m0 + arow) * H_DIM;

  floatx4 pg[4], pu[4];
  bf16x8 pa;
  #pragma unroll
  for (int p = 0; p < 4; ++p) {
    pg[p] = *(const floatx4*)(wgB + (size_t)(p * 16 + wrow) * H_DIM + wcol);
    pu[p] = *(const floatx4*)(wuB + (size_t)(p * 16 + wrow) * H_DIM + wcol);
  }
  pa = *(const bf16x8*)(aRow + acol);

  floatx4 ag0 = (floatx4)0.0f, ag1 = (floatx4)0.0f;
  floatx4 au0 = (floatx4)0.0f, au1 = (floatx4)0.0f;
  for (int k0 = 0; k0 < H_DIM; k0 += BK) {
    if (k0) __syncthreads();
    #pragma unroll
    for (int p = 0; p < 4; ++p) {
      *(ushort4v*)(sBg + (p * 16 + wrow) * LDB + wcol) = pack4(pg[p]);
      *(ushort4v*)(sBu + (p * 16 + wrow) * LDB + wcol) = pack4(pu[p]);
    }
    *(bf16x8*)(sA + arow * LDB + acol) = pa;
    __syncthreads();
    if (k0 + BK < H_DIM) {
      const int kn = k0 + BK;
      #pragma unroll
      for (int p = 0; p < 4; ++p) {
        pg[p] = *(const floatx4*)(wgB + (size_t)(p * 16 + wrow) * H_DIM + kn + wcol);
        pu[p] = *(const floatx4*)(wuB + (size_t)(p * 16 + wrow) * H_DIM + kn + wcol);
      }
      pa = *(const bf16x8*)(aRow + kn + acol);
    }
    #pragma unroll
    for (int kk = 0; kk < BK; kk += 32) {
      const int ko = kk + q * 8;
      bf16x8 bg = *(const bf16x8*)(sBg + (wv * 16 + c) * LDB + ko);
      bf16x8 bu = *(const bf16x8*)(sBu + (wv * 16 + c) * LDB + ko);
      bf16x8 a0 = *(const bf16x8*)(sA + c * LDB + ko);
      bf16x8 a1 = *(const bf16x8*)(sA + (16 + c) * LDB + ko);
      ag0 = mfma16(a0, bg, ag0);
      ag1 = mfma16(a1, bg, ag1);
      au0 = mfma16(a0, bu, au0);
      au1 = mfma16(a1, bu, au1);
    }
  }
  #pragma unroll
  for (int s = 0; s < 2; ++s) {
    floatx4 g = s ? ag1 : ag0;
    floatx4 u = s ? au1 : au0;
    #pragma unroll
    for (int r = 0; r < 4; ++r) {
      const int m = m0 + s * 16 + q * 4 + r;
      float gg = g[r], uu = u[r];
      float a = gg / (1.0f + __expf(-gg)) * uu;
      act_s[(size_t)m * SI_DIM + n0 + wv * 16 + c] = f2bf(a);
    }
  }
}

// ---------------------------------------------------------------------------
// Kernel 4: shared down; K-split x2, pipelined, atomicAdd into zeroed out.
// ---------------------------------------------------------------------------
__global__ __launch_bounds__(256, 2) void shared_down_kernel(
    const unsigned short* __restrict__ act_s, const float* __restrict__ wsd,
    float* __restrict__ out) {
  __shared__ unsigned short sB[BN * LDB];
  __shared__ unsigned short sA[BM * LDB];

  const int n0 = (blockIdx.x & 15) * BN;
  const int m0 = ((blockIdx.x >> 4) & 7) * BM;
  const int kh = blockIdx.x >> 7;
  const int kbeg = kh * (SI_DIM / 2);
  const int j = threadIdx.x;
  const int wv = j >> 6, lane = j & 63;
  const int q = lane >> 4, c = lane & 15;
  const float* wB = wsd + (size_t)n0 * SI_DIM;

  const int wrow = j >> 4, wcol = (j & 15) * 4;
  const int arow = j >> 3, acol = (j & 7) * 8;
  const unsigned short* aRow = act_s + (size_t)(m0 + arow) * SI_DIM;

  floatx4 pw[4];
  bf16x8 pa;
  #pragma unroll
  for (int p = 0; p < 4; ++p) {
    pw[p] = *(const floatx4*)(wB + (size_t)(p * 16 + wrow) * SI_DIM + kbeg + wcol);
  }
  pa = *(const bf16x8*)(aRow + kbeg + acol);

  floatx4 ac0 = (floatx4)0.0f, ac1 = (floatx4)0.0f;
  for (int kr = 0; kr < SI_DIM / 2; kr += BK) {
    const int k0 = kbeg + kr;
    if (kr) __syncthreads();
    #pragma unroll
    for (int p = 0; p < 4; ++p) {
      *(ushort4v*)(sB + (p * 16 + wrow) * LDB + wcol) = pack4(pw[p]);
    }
    *(bf16x8*)(sA + arow * LDB + acol) = pa;
    __syncthreads();
    if (kr + BK < SI_DIM / 2) {
      const int kn = k0 + BK;
      #pragma unroll
      for (int p = 0; p < 4; ++p) {
        pw[p] = *(const floatx4*)(wB + (size_t)(p * 16 + wrow) * SI_DIM + kn + wcol);
      }
      pa = *(const bf16x8*)(aRow + kn + acol);
    }
    #pragma unroll
    for (int kk = 0; kk < BK; kk += 32) {
      const int ko = kk + q * 8;
      bf16x8 b = *(const bf16x8*)(sB + (wv * 16 + c) * LDB + ko);
      bf16x8 a0 = *(const bf16x8*)(sA + c * LDB + ko);
      bf16x8 a1 = *(const bf16x8*)(sA + (16 + c) * LDB + ko);
      ac0 = mfma16(a0, b, ac0);
      ac1 = mfma16(a1, b, ac1);
    }
  }
  #pragma unroll
  for (int s = 0; s < 2; ++s) {
    floatx4 d = s ? ac1 : ac0;
    #pragma unroll
    for (int r = 0; r < 4; ++r) {
      const int m = m0 + s * 16 + q * 4 + r;
      atomicAdd(&out[(size_t)m * H_DIM + n0 + wv * 16 + c], d[r]);
    }
  }
}

// ---------------------------------------------------------------------------
// Kernel 5: routed down + weighted scatter-add, pipelined.
// ---------------------------------------------------------------------------
__global__ __launch_bounds__(256, 2) void routed_down_kernel(
    const unsigned short* __restrict__ act_r, const float* __restrict__ w2,
    const int* __restrict__ cnt, const int* __restrict__ tok_list,
    const float* __restrict__ wt_list, float* __restrict__ out) {
  __shared__ unsigned short sB[BN * LDB];
  __shared__ unsigned short sA[BM * LDB];
  __shared__ int stok[BM];
  __shared__ float swl[BM];

  const int e = blockIdx.x >> 4;
  const int n0 = (blockIdx.x & 15) * BN;
  const int j = threadIdx.x;
  const int wv = j >> 6, lane = j & 63;
  const int q = lane >> 4, c = lane & 15;
  const int ne = cnt[e];
  const int* tl = tok_list + e * T_TOK;
  const float* wl = wt_list + e * T_TOK;
  const unsigned short* apb = act_r + (size_t)e * T_TOK * I_DIM;
  const float* wB = w2 + ((size_t)e * H_DIM + n0) * I_DIM;

  const int wrow = j >> 4, wcol = (j & 15) * 4;
  const int arow = j >> 3, acol = (j & 7) * 8;

  for (int m0 = 0; m0 < ne; m0 += BM) {
    __syncthreads();
    if (j < BM) {
      int r = m0 + j;
      bool ok = r < ne;
      stok[j] = ok ? tl[r] : 0;
      swl[j] = ok ? wl[r] : 0.0f;
    }
    int ar = m0 + arow;
    if (ar >= T_TOK) ar = T_TOK - 1;
    const unsigned short* aRow = apb + (size_t)ar * I_DIM;

    floatx4 pw[4];
    bf16x8 pa;
    #pragma unroll
    for (int p = 0; p < 4; ++p) {
      pw[p] = *(const floatx4*)(wB + (size_t)(p * 16 + wrow) * I_DIM + wcol);
    }
    pa = *(const bf16x8*)(aRow + acol);

    floatx4 ac0 = (floatx4)0.0f, ac1 = (floatx4)0.0f;
    for (int k0 = 0; k0 < I_DIM; k0 += BK) {
      __syncthreads();  // k0=0: stok visible; else: prior MFMA done
      #pragma unroll
      for (int p = 0; p < 4; ++p) {
        *(ushort4v*)(sB + (p * 16 + wrow) * LDB + wcol) = pack4(pw[p]);
      }
      *(bf16x8*)(sA + arow * LDB + acol) = pa;
      __syncthreads();
      if (k0 + BK < I_DIM) {
        const int kn = k0 + BK;
        #pragma unroll
        for (int p = 0; p < 4; ++p) {
          pw[p] = *(const floatx4*)(wB + (size_t)(p * 16 + wrow) * I_DIM + kn + wcol);
        }
        pa = *(const bf16x8*)(aRow + kn + acol);
      }
      #pragma unroll
      for (int kk = 0; kk < BK; kk += 32) {
        const int ko = kk + q * 8;
        bf16x8 b = *(const bf16x8*)(sB + (wv * 16 + c) * LDB + ko);
        bf16x8 a0 = *(const bf16x8*)(sA + c * LDB + ko);
        bf16x8 a1 = *(const bf16x8*)(sA + (16 + c) * LDB + ko);
        ac0 = mfma16(a0, b, ac0);
        ac1 = mfma16(a1, b, ac1);
      }
    }
    #pragma unroll
    for (int s = 0; s < 2; ++s) {
      floatx4 d = s ? ac1 : ac0;
      #pragma unroll
      for (int r = 0; r < 4; ++r) {
        const int mi = s * 16 + q * 4 + r;
        if (m0 + mi < ne) {
          atomicAdd(&out[(size_t)stok[mi] * H_DIM + n0 + wv * 16 + c],
                    d[r] * swl[mi]);
        }
      }
    }
  }
}

extern "C" void kernel_launch(void* const* d_in, const int* in_sizes, int n_in,
                              void* d_out, int out_size, void* d_ws, size_t ws_size,
                              hipStream_t stream) {
  const float* x   = (const float*)d_in[0];
  const float* gw  = (const float*)d_in[1];
  const float* eb  = (const float*)d_in[2];
  const float* w1  = (const float*)d_in[3];
  const float* w3  = (const float*)d_in[4];
  const float* w2  = (const float*)d_in[5];
  const float* wsg = (const float*)d_in[6];
  const float* wsu = (const float*)d_in[7];
  const float* wsd = (const float*)d_in[8];
  float* out = (float*)d_out;

  char* ws = (char*)d_ws;
  unsigned short* xbf   = (unsigned short*)(ws);                 // 512 KB
  unsigned short* act_s = (unsigned short*)(ws + 524288);        // 1 MB
  int*   cnt            = (int*)(ws + 1572864);                  // 256 B
  int*   tok            = (int*)(ws + 1573120);                  // 64 KB
  float* wt             = (float*)(ws + 1638656);                // 64 KB
  unsigned short* act_r = (unsigned short*)(ws + 1704192);       // 16.8 MB

  hipMemsetAsync(cnt, 0, E_NUM * sizeof(int), stream);
  hipMemsetAsync(out, 0, (size_t)T_TOK * H_DIM * sizeof(float), stream);
  gate_route_kernel<<<dim3(T_TOK), dim3(256), 0, stream>>>(x, gw, eb, xbf, cnt, tok, wt);
  routed_gu_kernel<<<dim3(E_NUM * (I_DIM / BN)), dim3(256), 0, stream>>>(xbf, w1, w3, cnt, tok, act_r);
  shared_gu_kernel<<<dim3((SI_DIM / BN) * (T_TOK / BM)), dim3(256), 0, stream>>>(xbf, wsg, wsu, act_s);
  shared_down_kernel<<<dim3((H_DIM / BN) * (T_TOK / BM) * 2), dim3(256), 0, stream>>>(act_s, wsd, out);
  routed_down_kernel<<<dim3(E_NUM * (H_DIM / BN)), dim3(256), 0, stream>>>(act_r, w2, cnt, tok, wt, out);
}